// Round 1
// baseline (312.594 us; speedup 1.0000x reference)
//
#include <hip/hip_runtime.h>

// BondWeight: out[b, src+1, dst+1] = w and out[b, dst+1, src+1] = w,
// w = weights[bond_type], over a zeroed [B, N, N] f32 tensor.
// B=1024, E=512, T=8, N=256. Output = 256 MB -> HBM-write-bound (~41 us floor).
//
// Determinism: numpy ref semantics = pass1 (src,dst) last-edge-wins, then
// pass2 (dst,src) last-edge-wins overriding pass1. One thread per batch does
// both passes serially (per-location program order == reference order);
// batches own disjoint 256KB tiles, so no cross-thread races.

#define NB_E 512
#define NB_N 256

__global__ __launch_bounds__(256) void BondWeight_41738492182540_kernel(
    const float* __restrict__ weights,
    const int*   __restrict__ bsrc,
    const int*   __restrict__ bdst,
    const int*   __restrict__ btyp,
    float*       __restrict__ out)
{
    __shared__ int   s_off1[NB_E];
    __shared__ int   s_off2[NB_E];
    __shared__ float s_w[NB_E];

    const int b = blockIdx.x;
    const int t = threadIdx.x;
    float* __restrict__ tile = out + (size_t)b * (NB_N * NB_N);

    // --- Stage this batch's edges into LDS (coalesced global reads) ---
    const int ebase = b * NB_E;
    #pragma unroll
    for (int i = 0; i < NB_E / 256; ++i) {
        const int e  = t + 256 * i;
        const int si = bsrc[ebase + e] + 1;   // [1, 255]
        const int di = bdst[ebase + e] + 1;
        const int ty = btyp[ebase + e] & 7;   // T = 8
        const float w = weights[ty];
        s_off1[e] = si * NB_N + di;
        s_off2[e] = di * NB_N + si;
        s_w[e]    = w;
    }

    // --- Zero this batch's 256x256 tile: 16384 float4, 64 per thread ---
    const float4 z = make_float4(0.f, 0.f, 0.f, 0.f);
    float4* __restrict__ tile4 = (float4*)tile;
    #pragma unroll 8
    for (int k = 0; k < 64; ++k)
        tile4[t + 256 * k] = z;               // coalesced, stride 4KB per iter

    __syncthreads();  // emits s_waitcnt vmcnt(0) before s_barrier: zeros visible

    // --- Serial scatter by thread 0: exact reference write order ---
    if (t == 0) {
        #pragma unroll 8
        for (int e = 0; e < NB_E; ++e)        // pass 1: (src, dst)
            tile[s_off1[e]] = s_w[e];
        #pragma unroll 8
        for (int e = 0; e < NB_E; ++e)        // pass 2: (dst, src) overrides
            tile[s_off2[e]] = s_w[e];
    }
}

extern "C" void kernel_launch(void* const* d_in, const int* in_sizes, int n_in,
                              void* d_out, int out_size, void* d_ws, size_t ws_size,
                              hipStream_t stream) {
    const float* weights = (const float*)d_in[0];   // [T=8]
    const int*   bsrc    = (const int*)d_in[1];     // [B, E]
    const int*   bdst    = (const int*)d_in[2];     // [B, E]
    const int*   btyp    = (const int*)d_in[3];     // [B, E]
    float*       out     = (float*)d_out;           // [B, N, N] f32

    const int nb = in_sizes[1] / NB_E;              // B = 1024

    BondWeight_41738492182540_kernel<<<nb, 256, 0, stream>>>(
        weights, bsrc, bdst, btyp, out);
}

// Round 2
// 278.585 us; speedup vs baseline: 1.1221x; 1.1221x over previous
//
#include <hip/hip_runtime.h>

// BondWeight: out[b, src+1, dst+1] = w; out[b, dst+1, src+1] = w (two passes,
// last-write-wins within the 1024-write per-batch sequence, numpy semantics).
// B=1024, E=512, T=8, N=256. Output 256 MB f32 -> pure HBM-write-bound.
//
// Strategy: merge scatter into the streaming zero-write so every output line
// is written exactly once (no RMW, no serial tail). Per batch block, a u16
// LDS table over a 64-row chunk holds packed=(seq+1)<<3|type per cell; a
// CAS-based 16-bit max implements last-write-wins (seq strictly increasing
// dominates the comparison; type bits recover the weight). Stream the chunk
// as coalesced nontemporal float4 stores. 4 chunks cover the 256x256 tile.

#define NB_E 512
#define NB_N 256
#define CH_ROWS 64
#define CH_WORDS (CH_ROWS * NB_N / 2)   // 8192 u32 = 32 KB LDS

typedef float v4f __attribute__((ext_vector_type(4)));

__device__ __forceinline__ void lds_max_u16(unsigned int* tab, int cell, unsigned int v16)
{
    unsigned int* w = tab + (cell >> 1);
    const int sh = (cell & 1) * 16;
    unsigned int old = *w;
    while (true) {
        const unsigned int cur = (old >> sh) & 0xFFFFu;
        if (cur >= v16) break;                       // current winner is later
        const unsigned int nw = (old & ~(0xFFFFu << sh)) | (v16 << sh);
        const unsigned int seen = atomicCAS(w, old, nw);
        if (seen == old) break;
        old = seen;                                  // contended: retry
    }
}

__global__ __launch_bounds__(256) void BondWeight_41738492182540_kernel(
    const float* __restrict__ weights,
    const int*   __restrict__ bsrc,
    const int*   __restrict__ bdst,
    const int*   __restrict__ btyp,
    float*       __restrict__ out)
{
    __shared__ unsigned int seqtab[CH_WORDS];
    __shared__ float s_wt[8];

    const int b = blockIdx.x;
    const int t = threadIdx.x;

    if (t < 8) s_wt[t] = weights[t];

    // My two edges -> four writes. seq order: pass1 (src,dst) e=0..511 then
    // pass2 (dst,src) e=0..511. packed = (seq+1)<<3 | type; max == last wins.
    const int ebase = b * NB_E;
    int row[4], col[4];
    unsigned int pk[4];
    #pragma unroll
    for (int i = 0; i < 2; ++i) {
        const int e  = t + 256 * i;
        const int s1 = bsrc[ebase + e] + 1;          // [1, 255]
        const int d1 = bdst[ebase + e] + 1;
        const unsigned int ty = (unsigned int)btyp[ebase + e] & 7u;
        row[2*i]   = s1; col[2*i]   = d1; pk[2*i]   = ((unsigned int)(e + 1) << 3) | ty;
        row[2*i+1] = d1; col[2*i+1] = s1; pk[2*i+1] = ((unsigned int)(NB_E + e + 1) << 3) | ty;
    }

    float4* __restrict__ out4 = ((float4*)out) + (size_t)b * (NB_N * NB_N / 4);

    for (int r0 = 0; r0 < NB_N; r0 += CH_ROWS) {
        // --- zero the chunk table: 8192 u32, uint4 x 8 per thread ---
        uint4* tab4 = (uint4*)seqtab;
        #pragma unroll
        for (int k = 0; k < CH_WORDS / 4 / 256; ++k)
            tab4[t + 256 * k] = make_uint4(0u, 0u, 0u, 0u);
        __syncthreads();

        // --- scatter my writes that land in this row chunk ---
        #pragma unroll
        for (int i = 0; i < 4; ++i) {
            const int r = row[i] - r0;
            if (0 <= r && r < CH_ROWS)
                lds_max_u16(seqtab, r * NB_N + col[i], pk[i]);
        }
        __syncthreads();

        // --- stream chunk: 64 rows = 4096 float4, 16 per thread, coalesced ---
        #pragma unroll
        for (int k = 0; k < (CH_ROWS * NB_N / 4) / 256; ++k) {
            const int i4 = t + 256 * k;
            const unsigned int a  = seqtab[2 * i4];
            const unsigned int bb = seqtab[2 * i4 + 1];
            v4f v;
            unsigned int p;
            p = a & 0xFFFFu;  v.x = p ? s_wt[p & 7u] : 0.0f;
            p = a >> 16;      v.y = p ? s_wt[p & 7u] : 0.0f;
            p = bb & 0xFFFFu; v.z = p ? s_wt[p & 7u] : 0.0f;
            p = bb >> 16;     v.w = p ? s_wt[p & 7u] : 0.0f;
            __builtin_nontemporal_store(v, (v4f*)&out4[r0 * (NB_N / 4) + i4]);
        }
        __syncthreads();   // seqtab re-zeroed next iter: all reads must finish
    }
}

extern "C" void kernel_launch(void* const* d_in, const int* in_sizes, int n_in,
                              void* d_out, int out_size, void* d_ws, size_t ws_size,
                              hipStream_t stream) {
    const float* weights = (const float*)d_in[0];   // [T=8]
    const int*   bsrc    = (const int*)d_in[1];     // [B, E]
    const int*   bdst    = (const int*)d_in[2];     // [B, E]
    const int*   btyp    = (const int*)d_in[3];     // [B, E]
    float*       out     = (float*)d_out;           // [B, N, N] f32

    const int nb = in_sizes[1] / NB_E;              // B = 1024

    BondWeight_41738492182540_kernel<<<nb, 256, 0, stream>>>(
        weights, bsrc, bdst, btyp, out);
}

// Round 3
// 272.814 us; speedup vs baseline: 1.1458x; 1.0212x over previous
//
#include <hip/hip_runtime.h>

// BondWeight: out[b, src+1, dst+1] = w; out[b, dst+1, src+1] = w (two passes,
// last-write-wins within the 1024-write per-batch sequence, numpy semantics).
// B=1024, E=512, T=8, N=256. Output 256 MB f32 -> pure HBM-write-bound.
//
// Strategy: merge scatter into the streaming write so every output line is
// written exactly once. Per batch block, a u16 LDS table over a 64-row chunk
// holds packed=(seq+1)<<3|type per cell; CAS-based 16-bit max implements
// last-write-wins. Stream the chunk as coalesced float4 stores.
//
// R3 changes vs R2 (112 us kernel, vs ~42 us store floor):
//  - dropped __builtin_nontemporal_store: nt bypasses L2; the 6.4 TB/s
//    harness fill uses normal stores. Also makes barrier vmcnt drains cheap.
//  - seqtab pair read as one ds_read_b64 (uint2) instead of 2x b32.
//  - re-zero fused into the stream loop (each thread zeroes the exact words
//    it just read) -> single upfront zero phase, 9 barriers instead of 13.

#define NB_E 512
#define NB_N 256
#define CH_ROWS 64
#define CH_WORDS (CH_ROWS * NB_N / 2)   // 8192 u32 = 32 KB LDS

typedef float v4f __attribute__((ext_vector_type(4)));

__device__ __forceinline__ void lds_max_u16(unsigned int* tab, int cell, unsigned int v16)
{
    unsigned int* w = tab + (cell >> 1);
    const int sh = (cell & 1) * 16;
    unsigned int old = *w;
    while (true) {
        const unsigned int cur = (old >> sh) & 0xFFFFu;
        if (cur >= v16) break;                       // current winner is later
        const unsigned int nw = (old & ~(0xFFFFu << sh)) | (v16 << sh);
        const unsigned int seen = atomicCAS(w, old, nw);
        if (seen == old) break;
        old = seen;                                  // contended: retry
    }
}

__global__ __launch_bounds__(256) void BondWeight_41738492182540_kernel(
    const float* __restrict__ weights,
    const int*   __restrict__ bsrc,
    const int*   __restrict__ bdst,
    const int*   __restrict__ btyp,
    float*       __restrict__ out)
{
    __shared__ unsigned int seqtab[CH_WORDS];
    __shared__ float s_wt[8];

    const int b = blockIdx.x;
    const int t = threadIdx.x;

    if (t < 8) s_wt[t] = weights[t];

    // My two edges -> four writes. seq order: pass1 (src,dst) e=0..511 then
    // pass2 (dst,src) e=0..511. packed = (seq+1)<<3 | type; max == last wins.
    const int ebase = b * NB_E;
    int row[4], col[4];
    unsigned int pk[4];
    #pragma unroll
    for (int i = 0; i < 2; ++i) {
        const int e  = t + 256 * i;
        const int s1 = bsrc[ebase + e] + 1;          // [1, 255]
        const int d1 = bdst[ebase + e] + 1;
        const unsigned int ty = (unsigned int)btyp[ebase + e] & 7u;
        row[2*i]   = s1; col[2*i]   = d1; pk[2*i]   = ((unsigned int)(e + 1) << 3) | ty;
        row[2*i+1] = d1; col[2*i+1] = s1; pk[2*i+1] = ((unsigned int)(NB_E + e + 1) << 3) | ty;
    }

    // --- zero the table ONCE: 8192 u32, uint4 x 8 per thread ---
    {
        uint4* tab4 = (uint4*)seqtab;
        #pragma unroll
        for (int k = 0; k < CH_WORDS / 4 / 256; ++k)
            tab4[t + 256 * k] = make_uint4(0u, 0u, 0u, 0u);
    }
    __syncthreads();

    float4* __restrict__ out4 = ((float4*)out) + (size_t)b * (NB_N * NB_N / 4);
    uint2*  __restrict__ tab2 = (uint2*)seqtab;

    for (int r0 = 0; r0 < NB_N; r0 += CH_ROWS) {
        // --- scatter my writes that land in this row chunk (table is clean) ---
        #pragma unroll
        for (int i = 0; i < 4; ++i) {
            const int r = row[i] - r0;
            if (0 <= r && r < CH_ROWS)
                lds_max_u16(seqtab, r * NB_N + col[i], pk[i]);
        }
        __syncthreads();

        // --- stream chunk: 4096 float4, 16/thread, coalesced; re-zero as we go ---
        #pragma unroll
        for (int k = 0; k < (CH_ROWS * NB_N / 4) / 256; ++k) {
            const int i4 = t + 256 * k;
            const uint2 ab = tab2[i4];               // ds_read_b64
            tab2[i4] = make_uint2(0u, 0u);           // clean for next chunk's CAS
            v4f v;
            unsigned int p;
            p = ab.x & 0xFFFFu; v.x = p ? s_wt[p & 7u] : 0.0f;
            p = ab.x >> 16;     v.y = p ? s_wt[p & 7u] : 0.0f;
            p = ab.y & 0xFFFFu; v.z = p ? s_wt[p & 7u] : 0.0f;
            p = ab.y >> 16;     v.w = p ? s_wt[p & 7u] : 0.0f;
            *(v4f*)&out4[r0 * (NB_N / 4) + i4] = v;  // plain store: completes in L2
        }
        __syncthreads();   // stream+rezero done before next chunk's CAS
    }
}

extern "C" void kernel_launch(void* const* d_in, const int* in_sizes, int n_in,
                              void* d_out, int out_size, void* d_ws, size_t ws_size,
                              hipStream_t stream) {
    const float* weights = (const float*)d_in[0];   // [T=8]
    const int*   bsrc    = (const int*)d_in[1];     // [B, E]
    const int*   bdst    = (const int*)d_in[2];     // [B, E]
    const int*   btyp    = (const int*)d_in[3];     // [B, E]
    float*       out     = (float*)d_out;           // [B, N, N] f32

    const int nb = in_sizes[1] / NB_E;              // B = 1024

    BondWeight_41738492182540_kernel<<<nb, 256, 0, stream>>>(
        weights, bsrc, bdst, btyp, out);
}